// Round 2
// baseline (117.712 us; speedup 1.0000x reference)
//
#include <hip/hip_runtime.h>
#include <hip/hip_bf16.h>

typedef __bf16 bf16x8 __attribute__((ext_vector_type(8)));
typedef float f32x4 __attribute__((ext_vector_type(4)));

#define F_IN 128
#define HF 32  // H * F_OUT

__device__ inline bf16x8 cvt8(float4 a, float4 b) {
    bf16x8 r;
    r[0] = (__bf16)a.x; r[1] = (__bf16)a.y; r[2] = (__bf16)a.z; r[3] = (__bf16)a.w;
    r[4] = (__bf16)b.x; r[5] = (__bf16)b.y; r[6] = (__bf16)b.z; r[7] = (__bf16)b.w;
    return r;
}

// Kernel 1: mark nodes that appear as a source of at least one edge.
__global__ void mask_kernel(const int* __restrict__ src, int E,
                            unsigned char* __restrict__ mask) {
    int i = blockIdx.x * blockDim.x + threadIdx.x;
    int stride = gridDim.x * blockDim.x;
    for (; i < E; i += stride) mask[src[i]] = 1;
}

// Kernel 2: out[n,:] = (h_in[n,:] @ W^T + b) * (mask[n] ? 1 : 0)
// fp32 in/out; bf16 MFMA internally (2%-relative threshold covers rounding).
// Wave handles 32 nodes (2 m-tiles of 16), block = 4 waves = 128 nodes.
__global__ __launch_bounds__(256) void gat_gemm_kernel(
    const float* __restrict__ h_in, const float* __restrict__ W,
    const float* __restrict__ b, const unsigned char* __restrict__ mask,
    float* __restrict__ out, int N) {
    const int tid  = threadIdx.x;
    const int lane = tid & 63;
    const int wave = tid >> 6;
    const int q = lane >> 4;   // k-quad for A/B, row-quad for C/D
    const int c = lane & 15;   // m for A, n for B, col for C/D

    const int node_base = blockIdx.x * 128 + wave * 32;
    if (node_base >= N) return;

    // B fragments: B[k][n] = W[n][k]; W is [32][128] row-major (out x in).
    // Lane needs W[nt*16+c][ks*32 + q*8 .. +7] -> 8 consecutive floats.
    bf16x8 bfrag[2][4];
#pragma unroll
    for (int nt = 0; nt < 2; ++nt) {
        const float* wp = W + (nt * 16 + c) * F_IN + q * 8;
#pragma unroll
        for (int ks = 0; ks < 4; ++ks) {
            float4 f0 = *(const float4*)(wp + ks * 32);
            float4 f1 = *(const float4*)(wp + ks * 32 + 4);
            bfrag[nt][ks] = cvt8(f0, f1);
        }
    }

    // A fragments: A[m][k] = h_in[node_base + mt*16 + c][ks*32 + q*8 .. +7]
    bf16x8 afrag[2][4];
#pragma unroll
    for (int mt = 0; mt < 2; ++mt) {
        int row = node_base + mt * 16 + c;
        if (row > N - 1) row = N - 1;  // clamp; stores are guarded
        const float* hp = h_in + (long)row * F_IN + q * 8;
#pragma unroll
        for (int ks = 0; ks < 4; ++ks) {
            float4 f0 = *(const float4*)(hp + ks * 32);
            float4 f1 = *(const float4*)(hp + ks * 32 + 4);
            afrag[mt][ks] = cvt8(f0, f1);
        }
    }

    f32x4 acc[2][2] = {{{0.f, 0.f, 0.f, 0.f}, {0.f, 0.f, 0.f, 0.f}},
                       {{0.f, 0.f, 0.f, 0.f}, {0.f, 0.f, 0.f, 0.f}}};
#pragma unroll
    for (int ks = 0; ks < 4; ++ks)
#pragma unroll
        for (int mt = 0; mt < 2; ++mt)
#pragma unroll
            for (int nt = 0; nt < 2; ++nt)
                acc[mt][nt] = __builtin_amdgcn_mfma_f32_16x16x32_bf16(
                    afrag[mt][ks], bfrag[nt][ks], acc[mt][nt], 0, 0, 0);

    const float bias0 = b[c];
    const float bias1 = b[c + 16];

    // C/D layout: col = lane&15, row = q*4 + reg
#pragma unroll
    for (int mt = 0; mt < 2; ++mt) {
        int rowb = node_base + mt * 16 + q * 4;
#pragma unroll
        for (int r = 0; r < 4; ++r) {
            int row = rowb + r;
            if (row < N) {
                float s = mask[row] ? 1.0f : 0.0f;
                out[(long)row * HF + c]      = (acc[mt][0][r] + bias0) * s;
                out[(long)row * HF + 16 + c] = (acc[mt][1][r] + bias1) * s;
            }
        }
    }
}

extern "C" void kernel_launch(void* const* d_in, const int* in_sizes, int n_in,
                              void* d_out, int out_size, void* d_ws, size_t ws_size,
                              hipStream_t stream) {
    // Inputs (setup_inputs order): h_in, W, b, a_src, a_tgt, edge_index (all fp32 except edge_index)
    const float* h_in = (const float*)d_in[0];
    const float* W    = (const float*)d_in[1];
    const float* b    = (const float*)d_in[2];
    const int* edge_index = (const int*)d_in[5];

    const int N = in_sizes[0] / F_IN;
    const int E = in_sizes[5] / 2;  // edge_index is [2, E]; row 0 = src

    unsigned char* mask = (unsigned char*)d_ws;  // N bytes of scratch

    hipMemsetAsync(mask, 0, N, stream);

    int mb = (E + 255) / 256;
    if (mb > 2048) mb = 2048;
    mask_kernel<<<mb, 256, 0, stream>>>(edge_index, E, mask);

    int gb = (N + 127) / 128;
    gat_gemm_kernel<<<gb, 256, 0, stream>>>(h_in, W, b, mask,
                                            (float*)d_out, N);
}